// Round 4
// baseline (243.160 us; speedup 1.0000x reference)
//
#include <hip/hip_runtime.h>
#include <hip/hip_cooperative_groups.h>
#include <math.h>

namespace cg = cooperative_groups;

#define WIN 7
#define WPT 8               // windows per thread-item in fused SSIM phase
#define BLK 256
#define NBLK 1024           // 4 blocks/CU guaranteed by __launch_bounds__(256,4)
#define GSTRIDE (NBLK * BLK)

__device__ __forceinline__ float ssim_from(float sx, float sy, float sxx, float syy,
                                           float sxy, float C1, float C2) {
    const float inv7 = 1.0f / 7.0f;
    const float covn = 7.0f / 6.0f;
    float ux  = sx  * inv7;
    float uy  = sy  * inv7;
    float uxx = sxx * inv7;
    float uyy = syy * inv7;
    float uxy = sxy * inv7;
    float vx  = covn * (uxx - ux * ux);
    float vy  = covn * (uyy - uy * uy);
    float vxy = covn * (uxy - ux * uy);
    float A1 = 2.0f * ux * uy + C1;
    float A2 = 2.0f * vxy + C2;
    float B1 = ux * ux + uy * uy + C1;
    float B2 = vx + vy + C2;
    return (A1 * A2) * __builtin_amdgcn_rcpf(B1 * B2);
}

__global__ __launch_bounds__(BLK, 4)
void kfused(const float* __restrict__ x, const float* __restrict__ y, int n,
            float* __restrict__ partMax, float* __restrict__ blockSums,
            float* __restrict__ out) {
    cg::grid_group grid = cg::this_grid();
    const int tid = threadIdx.x;
    const int gid = blockIdx.x * BLK + tid;
    __shared__ float sm[4];
    __shared__ double sd[4];

    // ---------- Phase A: per-block partial max over y ----------
    float m = -__builtin_huge_valf();
    {
        const float4* y4 = (const float4*)y;
        int n4 = n >> 2;
        for (int i = gid; i < n4; i += GSTRIDE) {
            float4 v = y4[i];
            m = fmaxf(m, fmaxf(fmaxf(v.x, v.y), fmaxf(v.z, v.w)));
        }
        for (int i = (n4 << 2) + gid; i < n; i += GSTRIDE) m = fmaxf(m, y[i]);
    }
    #pragma unroll
    for (int off = 32; off; off >>= 1) m = fmaxf(m, __shfl_xor(m, off));
    if ((tid & 63) == 0) sm[tid >> 6] = m;
    __syncthreads();
    if (tid == 0)
        partMax[blockIdx.x] = fmaxf(fmaxf(sm[0], sm[1]), fmaxf(sm[2], sm[3]));
    grid.sync();

    // ---------- Phase B: every block reduces partMax (8 KB from L2) ----------
    float mm = -__builtin_huge_valf();
    #pragma unroll
    for (int i = 0; i < NBLK / BLK; i++) mm = fmaxf(mm, partMax[i * BLK + tid]);
    #pragma unroll
    for (int off = 32; off; off >>= 1) mm = fmaxf(mm, __shfl_xor(mm, off));
    if ((tid & 63) == 0) sm[tid >> 6] = mm;
    __syncthreads();
    const float dr = fmaxf(fmaxf(sm[0], sm[1]), fmaxf(sm[2], sm[3]));
    const float C1 = (0.01f * dr) * (0.01f * dr);
    const float C2 = (0.03f * dr) * (0.03f * dr);

    // ---------- Phase C: SSIM, WPT=8, software-pipelined redundant loads ----------
    const int nw = n - (WIN - 1);
    const int ninterior = (n >= 16) ? ((n - 16) / WPT + 1) : 0; // items with 16 floats in-bounds
    float acc = 0.0f;

    float4 cx0, cx1, cx2, cx3, cy0, cy1, cy2, cy3;
    int g = gid;
    bool have = (g < ninterior);
    if (have) {
        const float4* px = (const float4*)(x + g * WPT);
        cx0 = px[0]; cx1 = px[1]; cx2 = px[2]; cx3 = px[3];
        const float4* py = (const float4*)(y + g * WPT);
        cy0 = py[0]; cy1 = py[1]; cy2 = py[2]; cy3 = py[3];
    }
    while (have) {
        const int gn = g + GSTRIDE;
        const bool haven = (gn < ninterior);
        float4 nx0, nx1, nx2, nx3, ny0, ny1, ny2, ny3;
        if (haven) {                       // prefetch next item before computing current
            const float4* px = (const float4*)(x + gn * WPT);
            nx0 = px[0]; nx1 = px[1]; nx2 = px[2]; nx3 = px[3];
            const float4* py = (const float4*)(y + gn * WPT);
            ny0 = py[0]; ny1 = py[1]; ny2 = py[2]; ny3 = py[3];
        }
        // compute current item: windows [8g, 8g+8), floats [8g, 8g+15)
        {
            float xv[16], yv[16];
            xv[0]=cx0.x; xv[1]=cx0.y; xv[2]=cx0.z; xv[3]=cx0.w;
            xv[4]=cx1.x; xv[5]=cx1.y; xv[6]=cx1.z; xv[7]=cx1.w;
            xv[8]=cx2.x; xv[9]=cx2.y; xv[10]=cx2.z; xv[11]=cx2.w;
            xv[12]=cx3.x; xv[13]=cx3.y; xv[14]=cx3.z; xv[15]=cx3.w;
            yv[0]=cy0.x; yv[1]=cy0.y; yv[2]=cy0.z; yv[3]=cy0.w;
            yv[4]=cy1.x; yv[5]=cy1.y; yv[6]=cy1.z; yv[7]=cy1.w;
            yv[8]=cy2.x; yv[9]=cy2.y; yv[10]=cy2.z; yv[11]=cy2.w;
            yv[12]=cy3.x; yv[13]=cy3.y; yv[14]=cy3.z; yv[15]=cy3.w;

            float sx = 0.f, sy = 0.f, sxx = 0.f, syy = 0.f, sxy = 0.f;
            #pragma unroll
            for (int k = 0; k < WIN; k++) {
                float a = xv[k], b = yv[k];
                sx += a; sy += b;
                sxx = fmaf(a, a, sxx);
                syy = fmaf(b, b, syy);
                sxy = fmaf(a, b, sxy);
            }
            #pragma unroll
            for (int j = 0; j < WPT; j++) {
                acc += ssim_from(sx, sy, sxx, syy, sxy, C1, C2);
                if (j < WPT - 1) {
                    float ao = xv[j], an = xv[j + WIN];
                    float bo = yv[j], bn = yv[j + WIN];
                    sx += an - ao;
                    sy += bn - bo;
                    sxx += fmaf(an, an, -(ao * ao));
                    syy += fmaf(bn, bn, -(bo * bo));
                    sxy += fmaf(an, bn, -(ao * bo));
                }
            }
        }
        cx0 = nx0; cx1 = nx1; cx2 = nx2; cx3 = nx3;
        cy0 = ny0; cy1 = ny1; cy2 = ny2; cy3 = ny3;
        g = gn; have = haven;
    }
    // tail windows [ninterior*WPT, nw): at most WPT+1 of them, one thread, scalar
    if (gid == 0) {
        for (int w = ninterior * WPT; w < nw; ++w) {
            float sx = 0.f, sy = 0.f, sxx = 0.f, syy = 0.f, sxy = 0.f;
            for (int k = 0; k < WIN; k++) {
                float a = x[w + k], b = y[w + k];
                sx += a; sy += b;
                sxx = fmaf(a, a, sxx);
                syy = fmaf(b, b, syy);
                sxy = fmaf(a, b, sxy);
            }
            acc += ssim_from(sx, sy, sxx, syy, sxy, C1, C2);
        }
    }

    #pragma unroll
    for (int off = 32; off; off >>= 1) acc += __shfl_xor(acc, off);
    __syncthreads();            // protect sm reuse across async threads
    if ((tid & 63) == 0) sm[tid >> 6] = acc;
    __syncthreads();
    if (tid == 0)
        blockSums[blockIdx.x] = (sm[0] + sm[1]) + (sm[2] + sm[3]);
    grid.sync();

    // ---------- Phase D: block 0 reduces blockSums in double ----------
    if (blockIdx.x == 0) {
        double s = 0.0;
        #pragma unroll
        for (int i = 0; i < NBLK / BLK; i++) s += (double)blockSums[i * BLK + tid];
        #pragma unroll
        for (int off = 32; off; off >>= 1) s += __shfl_xor(s, off);
        if ((tid & 63) == 0) sd[tid >> 6] = s;
        __syncthreads();
        if (tid == 0)
            out[0] = (float)(((sd[0] + sd[1]) + (sd[2] + sd[3])) / (double)nw);
    }
}

// ---------------- fallback path (non-cooperative), round-3 structure ----------------
__global__ __launch_bounds__(BLK) void kmax_partial(const float* __restrict__ y, int n,
                                                    float* __restrict__ outMax) {
    int tid = blockIdx.x * blockDim.x + threadIdx.x;
    int stride = gridDim.x * blockDim.x;
    int n4 = n >> 2;
    const float4* y4 = (const float4*)y;
    float m = -__builtin_huge_valf();
    for (int i = tid; i < n4; i += stride) {
        float4 v = y4[i];
        m = fmaxf(m, fmaxf(fmaxf(v.x, v.y), fmaxf(v.z, v.w)));
    }
    for (int i = (n4 << 2) + tid; i < n; i += stride) m = fmaxf(m, y[i]);
    #pragma unroll
    for (int off = 32; off; off >>= 1) m = fmaxf(m, __shfl_xor(m, off));
    __shared__ float sm[4];
    if ((threadIdx.x & 63) == 0) sm[threadIdx.x >> 6] = m;
    __syncthreads();
    if (threadIdx.x == 0)
        outMax[blockIdx.x] = fmaxf(fmaxf(sm[0], sm[1]), fmaxf(sm[2], sm[3]));
}

__global__ __launch_bounds__(BLK) void kmax_final(const float* __restrict__ part, int np,
                                                  float* __restrict__ outMax) {
    float m = -__builtin_huge_valf();
    for (int i = threadIdx.x; i < np; i += BLK) m = fmaxf(m, part[i]);
    #pragma unroll
    for (int off = 32; off; off >>= 1) m = fmaxf(m, __shfl_xor(m, off));
    __shared__ float sm[4];
    if ((threadIdx.x & 63) == 0) sm[threadIdx.x >> 6] = m;
    __syncthreads();
    if (threadIdx.x == 0)
        outMax[0] = fmaxf(fmaxf(sm[0], sm[1]), fmaxf(sm[2], sm[3]));
}

__global__ __launch_bounds__(BLK) void kssim_fb(const float* __restrict__ x,
                                                const float* __restrict__ y,
                                                const float* __restrict__ maxPtr, int n,
                                                float* __restrict__ blockSums) {
    const int nw = n - (WIN - 1);
    const int ninterior = (n >= 16) ? ((n - 16) / WPT + 1) : 0;
    float dr = maxPtr[0];
    float C1 = (0.01f * dr) * (0.01f * dr);
    float C2 = (0.03f * dr) * (0.03f * dr);
    float acc = 0.0f;
    int stride = gridDim.x * blockDim.x;
    for (int g = blockIdx.x * blockDim.x + threadIdx.x; g < ninterior; g += stride) {
        const float4* px = (const float4*)(x + g * WPT);
        float4 a0 = px[0], a1 = px[1], a2 = px[2], a3 = px[3];
        const float4* py = (const float4*)(y + g * WPT);
        float4 b0 = py[0], b1 = py[1], b2 = py[2], b3 = py[3];
        float xv[16] = {a0.x,a0.y,a0.z,a0.w,a1.x,a1.y,a1.z,a1.w,
                        a2.x,a2.y,a2.z,a2.w,a3.x,a3.y,a3.z,a3.w};
        float yv[16] = {b0.x,b0.y,b0.z,b0.w,b1.x,b1.y,b1.z,b1.w,
                        b2.x,b2.y,b2.z,b2.w,b3.x,b3.y,b3.z,b3.w};
        float sx=0.f, sy=0.f, sxx=0.f, syy=0.f, sxy=0.f;
        #pragma unroll
        for (int k = 0; k < WIN; k++) {
            float a = xv[k], b = yv[k];
            sx += a; sy += b;
            sxx = fmaf(a,a,sxx); syy = fmaf(b,b,syy); sxy = fmaf(a,b,sxy);
        }
        #pragma unroll
        for (int j = 0; j < WPT; j++) {
            acc += ssim_from(sx, sy, sxx, syy, sxy, C1, C2);
            if (j < WPT - 1) {
                float ao = xv[j], an = xv[j+WIN], bo = yv[j], bn = yv[j+WIN];
                sx += an - ao; sy += bn - bo;
                sxx += fmaf(an,an,-(ao*ao));
                syy += fmaf(bn,bn,-(bo*bo));
                sxy += fmaf(an,bn,-(ao*bo));
            }
        }
    }
    if (blockIdx.x == 0 && threadIdx.x == 0) {
        for (int w = ninterior * WPT; w < nw; ++w) {
            float sx=0.f, sy=0.f, sxx=0.f, syy=0.f, sxy=0.f;
            for (int k = 0; k < WIN; k++) {
                float a = x[w+k], b = y[w+k];
                sx += a; sy += b;
                sxx = fmaf(a,a,sxx); syy = fmaf(b,b,syy); sxy = fmaf(a,b,sxy);
            }
            acc += ssim_from(sx, sy, sxx, syy, sxy, C1, C2);
        }
    }
    #pragma unroll
    for (int off = 32; off; off >>= 1) acc += __shfl_xor(acc, off);
    __shared__ float sm[4];
    if ((threadIdx.x & 63) == 0) sm[threadIdx.x >> 6] = acc;
    __syncthreads();
    if (threadIdx.x == 0)
        blockSums[blockIdx.x] = (sm[0] + sm[1]) + (sm[2] + sm[3]);
}

__global__ __launch_bounds__(BLK) void kfinal(const float* __restrict__ blockSums, int nb,
                                              float* __restrict__ out, int nw) {
    double s = 0.0;
    for (int i = threadIdx.x; i < nb; i += BLK) s += (double)blockSums[i];
    #pragma unroll
    for (int off = 32; off; off >>= 1) s += __shfl_xor(s, off);
    __shared__ double sd[4];
    if ((threadIdx.x & 63) == 0) sd[threadIdx.x >> 6] = s;
    __syncthreads();
    if (threadIdx.x == 0)
        out[0] = (float)(((sd[0] + sd[1]) + (sd[2] + sd[3])) / (double)nw);
}

extern "C" void kernel_launch(void* const* d_in, const int* in_sizes, int n_in,
                              void* d_out, int out_size, void* d_ws, size_t ws_size,
                              hipStream_t stream) {
    const float* x = (const float*)d_in[0];
    const float* y = (const float*)d_in[1];
    float* out = (float*)d_out;
    int n = in_sizes[0];
    int nw = n - (WIN - 1);

    float* wsf = (float*)d_ws;
    float* partMax   = wsf;           // NBLK floats
    float* blockSums = wsf + NBLK;    // NBLK floats

    void* args[] = { (void*)&x, (void*)&y, (void*)&n,
                     (void*)&partMax, (void*)&blockSums, (void*)&out };
    hipError_t err = hipLaunchCooperativeKernel((const void*)kfused, dim3(NBLK), dim3(BLK),
                                                args, 0, stream);
    if (err != hipSuccess) {
        // fallback: non-cooperative 4-kernel path
        kmax_partial<<<NBLK, BLK, 0, stream>>>(y, n, partMax);
        kmax_final<<<1, BLK, 0, stream>>>(partMax, NBLK, blockSums + NBLK); // scalar max
        kssim_fb<<<NBLK, BLK, 0, stream>>>(x, y, blockSums + NBLK, n, blockSums);
        kfinal<<<1, BLK, 0, stream>>>(blockSums, NBLK, out, nw);
    }
}

// Round 5
// 43.580 us; speedup vs baseline: 5.5796x; 5.5796x over previous
//
#include <hip/hip_runtime.h>
#include <math.h>

#define WIN 7
#define WPT 8               // windows per thread-item
#define BLK 256
#define NB 2048             // blocks for kmax_partial and kssim
#define GSTRIDE (NB * BLK)

__device__ __forceinline__ float max4(float4 v) {
    return fmaxf(fmaxf(v.x, v.y), fmaxf(v.z, v.w));
}

// SSIM for one window, from plain sums (P=sum x, Q=sum y, sxx, syy, sxy).
// Pre-scaled constants: c1=49*C1, c1d=2*c1, c2a=21*C2, c2b=42*C2.
// S = (2PQ+49C1)(7sxy-PQ+21C2)*2 / ((P^2+Q^2+49C1)(7(sxx+syy)-(P^2+Q^2)+42C2))
__device__ __forceinline__ float ssim_win(float P, float Q, float sxx, float syy, float sxy,
                                          float c1, float c1d, float c2a, float c2b) {
    float t1 = P * Q;
    float u  = fmaf(P, P, Q * Q);
    float A1 = fmaf(t1, 4.0f, c1d);          // 2*(2PQ + 49C1)
    float A2 = fmaf(sxy, 7.0f, c2a - t1);    // 7sxy - PQ + 21C2
    float B1 = u + c1;
    float B2 = fmaf(sxx + syy, 7.0f, c2b - u);
    return (A1 * A2) * __builtin_amdgcn_rcpf(B1 * B2);
}

// one item = WPT consecutive windows from 16 register-resident floats per array
__device__ __forceinline__ float compute_item(float4 x0, float4 x1, float4 x2, float4 x3,
                                              float4 y0, float4 y1, float4 y2, float4 y3,
                                              float c1, float c1d, float c2a, float c2b) {
    float xv[16] = {x0.x,x0.y,x0.z,x0.w, x1.x,x1.y,x1.z,x1.w,
                    x2.x,x2.y,x2.z,x2.w, x3.x,x3.y,x3.z,x3.w};
    float yv[16] = {y0.x,y0.y,y0.z,y0.w, y1.x,y1.y,y1.z,y1.w,
                    y2.x,y2.y,y2.z,y2.w, y3.x,y3.y,y3.z,y3.w};
    float P = 0.f, Q = 0.f, sxx = 0.f, syy = 0.f, sxy = 0.f;
    #pragma unroll
    for (int k = 0; k < WIN; k++) {
        float a = xv[k], b = yv[k];
        P += a; Q += b;
        sxx = fmaf(a, a, sxx);
        syy = fmaf(b, b, syy);
        sxy = fmaf(a, b, sxy);
    }
    float r = 0.f;
    #pragma unroll
    for (int j = 0; j < WPT; j++) {
        r += ssim_win(P, Q, sxx, syy, sxy, c1, c1d, c2a, c2b);
        if (j < WPT - 1) {
            float ao = xv[j], an = xv[j + WIN];
            float bo = yv[j], bn = yv[j + WIN];
            P += an - ao;
            Q += bn - bo;
            sxx += fmaf(an, an, -(ao * ao));
            syy += fmaf(bn, bn, -(bo * bo));
            sxy += fmaf(an, bn, -(ao * bo));
        }
    }
    return r;
}

__global__ __launch_bounds__(BLK) void kmax_partial(const float* __restrict__ y, int n,
                                                    float* __restrict__ outMax) {
    const int gid = blockIdx.x * BLK + threadIdx.x;
    const int n4 = n >> 2;
    const float4* y4 = (const float4*)y;
    float m0 = -__builtin_huge_valf(), m1 = m0;
    int i = gid;
    for (; i + GSTRIDE < n4; i += 2 * GSTRIDE) {
        float4 a = y4[i];
        float4 b = y4[i + GSTRIDE];
        m0 = fmaxf(m0, max4(a));
        m1 = fmaxf(m1, max4(b));
    }
    for (; i < n4; i += GSTRIDE) m0 = fmaxf(m0, max4(y4[i]));
    for (int j = (n4 << 2) + gid; j < n; j += GSTRIDE) m0 = fmaxf(m0, y[j]);
    float m = fmaxf(m0, m1);
    #pragma unroll
    for (int off = 32; off; off >>= 1) m = fmaxf(m, __shfl_xor(m, off));
    __shared__ float sm[4];
    if ((threadIdx.x & 63) == 0) sm[threadIdx.x >> 6] = m;
    __syncthreads();
    if (threadIdx.x == 0)
        outMax[blockIdx.x] = fmaxf(fmaxf(sm[0], sm[1]), fmaxf(sm[2], sm[3]));
}

__global__ __launch_bounds__(BLK) void kssim(const float* __restrict__ x,
                                             const float* __restrict__ y,
                                             const float* __restrict__ partMax, int n,
                                             int ninterior, int nfull, int rem,
                                             float* __restrict__ blockSums) {
    const int tid = threadIdx.x;
    const int gid = blockIdx.x * BLK + tid;
    __shared__ float sm[4];

    // ---- block-local finalize of max(y) (8 KB, L2-hot) ----
    float mm = -__builtin_huge_valf();
    #pragma unroll
    for (int i = 0; i < NB / BLK; i++) mm = fmaxf(mm, partMax[i * BLK + tid]);
    #pragma unroll
    for (int off = 32; off; off >>= 1) mm = fmaxf(mm, __shfl_xor(mm, off));
    if ((tid & 63) == 0) sm[tid >> 6] = mm;
    __syncthreads();
    const float dr = fmaxf(fmaxf(sm[0], sm[1]), fmaxf(sm[2], sm[3]));
    const float C1 = (0.01f * dr) * (0.01f * dr);
    const float C2 = (0.03f * dr) * (0.03f * dr);
    const float c1  = 49.0f * C1;
    const float c1d = 2.0f * c1;
    const float c2a = 21.0f * C2;
    const float c2b = 42.0f * C2;

    // ---- main: fixed-trip-count prefetch pipeline, no shuffles, no LDS ----
    float acc = 0.0f;
    int g = gid;
    float4 ax0, ax1, ax2, ax3, ay0, ay1, ay2, ay3;
    if (g < ninterior) {
        const float4* px = (const float4*)(x + g * WPT);
        ax0 = px[0]; ax1 = px[1]; ax2 = px[2]; ax3 = px[3];
        const float4* py = (const float4*)(y + g * WPT);
        ay0 = py[0]; ay1 = py[1]; ay2 = py[2]; ay3 = py[3];
    }
    for (int k = 0; k < nfull; k++) {
        const int gn = g + GSTRIDE;
        const bool nextExists = (k + 1 < nfull) || (gid < rem);
        float4 bx0, bx1, bx2, bx3, by0, by1, by2, by3;
        if (nextExists) {                 // issue next item's loads before compute
            const float4* px = (const float4*)(x + gn * WPT);
            bx0 = px[0]; bx1 = px[1]; bx2 = px[2]; bx3 = px[3];
            const float4* py = (const float4*)(y + gn * WPT);
            by0 = py[0]; by1 = py[1]; by2 = py[2]; by3 = py[3];
        }
        acc += compute_item(ax0, ax1, ax2, ax3, ay0, ay1, ay2, ay3, c1, c1d, c2a, c2b);
        ax0 = bx0; ax1 = bx1; ax2 = bx2; ax3 = bx3;
        ay0 = by0; ay1 = by1; ay2 = by2; ay3 = by3;
        g = gn;
    }
    if (gid < rem)   // prefetched tail item (or the prologue item when nfull==0)
        acc += compute_item(ax0, ax1, ax2, ax3, ay0, ay1, ay2, ay3, c1, c1d, c2a, c2b);

    // tail windows not covered by items (< WPT+1 of them): thread 0, scalar
    if (gid == 0) {
        const int nw = n - (WIN - 1);
        for (int w = ninterior * WPT; w < nw; ++w) {
            float P = 0.f, Q = 0.f, sxx = 0.f, syy = 0.f, sxy = 0.f;
            for (int k = 0; k < WIN; k++) {
                float a = x[w + k], b = y[w + k];
                P += a; Q += b;
                sxx = fmaf(a, a, sxx);
                syy = fmaf(b, b, syy);
                sxy = fmaf(a, b, sxy);
            }
            acc += ssim_win(P, Q, sxx, syy, sxy, c1, c1d, c2a, c2b);
        }
    }

    #pragma unroll
    for (int off = 32; off; off >>= 1) acc += __shfl_xor(acc, off);
    __syncthreads();          // sm reused
    if ((tid & 63) == 0) sm[tid >> 6] = acc;
    __syncthreads();
    if (tid == 0)
        blockSums[blockIdx.x] = (sm[0] + sm[1]) + (sm[2] + sm[3]);
}

__global__ __launch_bounds__(BLK) void kfinal(const float* __restrict__ blockSums, int nb,
                                              float* __restrict__ out, int nw) {
    double s = 0.0;
    for (int i = threadIdx.x; i < nb; i += BLK) s += (double)blockSums[i];
    #pragma unroll
    for (int off = 32; off; off >>= 1) s += __shfl_xor(s, off);
    __shared__ double sd[4];
    if ((threadIdx.x & 63) == 0) sd[threadIdx.x >> 6] = s;
    __syncthreads();
    if (threadIdx.x == 0)
        out[0] = (float)(((sd[0] + sd[1]) + (sd[2] + sd[3])) / (double)nw);
}

extern "C" void kernel_launch(void* const* d_in, const int* in_sizes, int n_in,
                              void* d_out, int out_size, void* d_ws, size_t ws_size,
                              hipStream_t stream) {
    const float* x = (const float*)d_in[0];
    const float* y = (const float*)d_in[1];
    float* out = (float*)d_out;
    int n = in_sizes[0];
    int nw = n - (WIN - 1);
    int ninterior = (n >= 16) ? ((n - 16) / WPT + 1) : 0;
    int nfull = ninterior / GSTRIDE;
    int rem   = ninterior - nfull * GSTRIDE;

    float* wsf = (float*)d_ws;
    float* partMax   = wsf;          // NB floats
    float* blockSums = wsf + NB;     // NB floats

    kmax_partial<<<NB, BLK, 0, stream>>>(y, n, partMax);
    kssim<<<NB, BLK, 0, stream>>>(x, y, partMax, n, ninterior, nfull, rem, blockSums);
    kfinal<<<1, BLK, 0, stream>>>(blockSums, NB, out, nw);
}